// Round 3
// baseline (321.649 us; speedup 1.0000x reference)
//
#include <hip/hip_runtime.h>
#include <stdint.h>

#define DM 1024
#define LS 2048
#define RMS_EPS 1.1920928955078125e-07f
#define S2 0.0029296875f   // BC_SCALE^2 = 3/1024, exact in fp32

typedef __attribute__((ext_vector_type(8))) short bf16x8;
typedef __attribute__((ext_vector_type(4))) float f32x4;

__device__ __forceinline__ unsigned short f2bf(float f) {
  uint32_t u = __builtin_bit_cast(uint32_t, f);
  u += 0x7FFFu + ((u >> 16) & 1u);   // round-to-nearest-even
  return (unsigned short)(u >> 16);
}

// ---------------------------------------------------------------------------
// K0: pack B (64x1024) and C (64x1024) fp32 -> stacked bf16 [128][1024]
// ---------------------------------------------------------------------------
__global__ __launch_bounds__(256) void k0_prep(const float* __restrict__ B,
                                               const float* __restrict__ C,
                                               unsigned short* __restrict__ Bbf) {
  int i4 = blockIdx.x * 256 + threadIdx.x;          // 0..32767 float4s
  const float4* src = (i4 < 16384) ? (const float4*)B : (const float4*)C;
  float4 v = src[i4 & 16383];
  ushort4 o;
  o.x = f2bf(v.x); o.y = f2bf(v.y); o.z = f2bf(v.z); o.w = f2bf(v.w);
  ((ushort4*)Bbf)[i4] = o;
}

// ---------------------------------------------------------------------------
// K1 v3: BuCuT[b][l][128] = ([B;C] @ u[b])^T via mfma_f32_16x16x32_bf16.
// grid (128,4)=512 blocks (2/CU), block 512 (8 waves -> 16 waves/CU).
// Wave w stages k8 in [16w,16w+16) and computes rows [16w,16w+16) x 16 cols.
// LDS tile[k8][col^ (k8&3)] holds the exact MFMA B-fragment (1 ds_read_b128),
// xor swizzle spreads bank groups evenly for both write and read phases.
// ---------------------------------------------------------------------------
__global__ __launch_bounds__(512) void k1_gemm(const float* __restrict__ u,
                                               const unsigned short* __restrict__ Bbf,
                                               float* __restrict__ BuCuT) {
  const int b    = blockIdx.y;
  const int l0   = blockIdx.x * 16;
  const int lane = threadIdx.x & 63;
  const int w    = threadIdx.x >> 6;     // 0..7
  const float* ub = u + (size_t)b * DM * LS;

  __shared__ bf16x8 tile[128][16];       // 32 KB

  { // ---- stage ----
    const int lq = lane & 3;             // col quad: cols 4lq..4lq+3
    const int kg = lane >> 2;            // 0..15
    const int k8 = 16*w + kg;            // 0..127
    float4 vv[8];
    #pragma unroll
    for (int r = 0; r < 8; ++r)
      vv[r] = *(const float4*)(ub + (size_t)(8*k8 + r) * LS + l0 + 4*lq);
    #pragma unroll
    for (int c = 0; c < 4; ++c) {
      union { bf16x8 v; unsigned short s[8]; } t;
      #pragma unroll
      for (int r = 0; r < 8; ++r) t.s[r] = f2bf(((const float*)&vv[r])[c]);
      tile[k8][(4*lq + c) ^ (k8 & 3)] = t.v;
    }
  }
  __syncthreads();

  // ---- compute: 16 rows per wave, N=16, K=1024 ----
  const int n = lane & 15;
  const int q = lane >> 4;
  f32x4 acc = {};
  const unsigned short* arow = Bbf + (size_t)(16*w + n) * DM + 8*q;
  #pragma unroll 4
  for (int it = 0; it < 32; ++it) {
    bf16x8 bfrag = tile[4*it + q][n ^ q];          // col n after swizzle
    bf16x8 a = *(const bf16x8*)(arow + 32*it);
    acc = __builtin_amdgcn_mfma_f32_16x16x32_bf16(a, bfrag, acc, 0, 0, 0);
  }
  float* ob = BuCuT + (size_t)b * LS * 128;
  // C/D: col = lane&15, row = 4q+reg -> global row 16w+4q+reg
  *(f32x4*)(ob + (size_t)(l0 + n) * 128 + 16*w + 4*q) = acc;
}

// ---------------------------------------------------------------------------
// K2 v2: Kw[b][t][j] = S2 * sum_n Cu[n,t] * A[n]^j * Bu[n,t-j], j=0..15,
// emitted PACKED as bf16 pairs: word jp = bf16(Kw[2jp]) | bf16(Kw[2jp+1])<<16.
// grid (128,4)=512 blocks, block 256; t-tile 16. Stage Bu/Cu transposed in
// LDS (reads are broadcast/conflict-free), A^j table in LDS; thread=(t,j).
// ---------------------------------------------------------------------------
__global__ __launch_bounds__(256) void k2_kw(const float* __restrict__ BuCuT,
                                             const float* __restrict__ A,
                                             uint32_t* __restrict__ Kwp) {
  const int b  = blockIdx.y;
  const int t0 = blockIdx.x * 16;
  const int tid = threadIdx.x;
  __shared__ float BuT[64][33];
  __shared__ float CuT[64][33];
  __shared__ float apow[64][17];
  __shared__ float ss2[16][17];
  const float* base = BuCuT + (size_t)b * LS * 128;

  #pragma unroll
  for (int i = 0; i < 4; ++i) {
    int idx = tid + 256*i;          // 0..1023
    int rl  = idx >> 5;             // local row 0..31  (global t0-16+rl)
    int f4  = idx & 31;             // float4 index within 128 cols
    int grow = t0 - 16 + rl;
    float4 v = (grow >= 0) ? *(const float4*)(base + (size_t)grow * 128 + 4*f4)
                           : make_float4(0.f, 0.f, 0.f, 0.f);
    int c0 = 4*f4;
    #pragma unroll
    for (int e = 0; e < 4; ++e) {
      int c = c0 + e;
      float val = ((const float*)&v)[e];
      if (c < 64) BuT[c][rl] = val; else CuT[c - 64][rl] = val;
    }
  }
  if (tid < 64) {
    float a = A[tid], p = 1.f;
    #pragma unroll
    for (int j = 0; j < 16; ++j) { apow[tid][j] = p; p *= a; }
  }
  __syncthreads();

  const int t = tid & 15, j = tid >> 4;
  const int rb = 16 + t - j;        // Bu row (>=1)
  float s = 0.f;
  #pragma unroll 8
  for (int n = 0; n < 64; ++n)
    s = fmaf(CuT[n][16 + t] * apow[n][j], BuT[n][rb], s);
  ss2[t][j] = s * S2;
  __syncthreads();

  if (tid < 128) {
    int tt = tid >> 3, jp = tid & 7;
    uint32_t pk = (uint32_t)f2bf(ss2[tt][2*jp])
                | ((uint32_t)f2bf(ss2[tt][2*jp + 1]) << 16);
    Kwp[((size_t)b * LS + t0 + tt) * 8 + jp] = pk;
  }
}

// ---------------------------------------------------------------------------
// K3 v3: fused conv(W=16) + u*D skip + RMSNorm(d) + norm_w + store.
// grid (256,4)=1024 blocks (4/CU), block 256, t-tile 8.
// thread: tg=tid&1 -> 4 consecutive t (offset 4*tg), dr=tid>>1 -> 8 d-rows.
// Kw held PACKED bf16 (32 regs), y[8][4]=32 regs -> ~100 VGPR, 4 waves/SIMD.
// ---------------------------------------------------------------------------
__global__ __launch_bounds__(256, 4) void k3_conv(const float* __restrict__ u,
                                                  const uint32_t* __restrict__ Kwp,
                                                  const float* __restrict__ Dv,
                                                  const float* __restrict__ nw,
                                                  float* __restrict__ out) {
  const int b  = blockIdx.y;
  const int t0 = blockIdx.x * 8;
  const int tg = threadIdx.x & 1;
  const int dr = threadIdx.x >> 1;          // 0..127
  const float* ub = u + (size_t)b * DM * LS;
  float* ob = out + (size_t)b * DM * LS;

  uint32_t kwp[4][8];
  #pragma unroll
  for (int k = 0; k < 4; ++k) {
    const uint32_t* kp = Kwp + ((size_t)b * LS + t0 + 4*tg + k) * 8;
    *(uint4*)&kwp[k][0] = *(const uint4*)kp;
    *(uint4*)&kwp[k][4] = *(const uint4*)(kp + 4);
  }

  const int cbase = t0 - 16 + 4*tg;         // aligned window start
  float y[8][4];
  float ps[4] = {0.f, 0.f, 0.f, 0.f};
  #pragma unroll
  for (int c = 0; c < 8; ++c) {
    const int d = dr + 128*c;
    const float* row = ub + (size_t)d * LS;
    float wr[20];
    #pragma unroll
    for (int s5 = 0; s5 < 5; ++s5) {
      int g = cbase + 4*s5;
      float4 v = (g >= 0) ? *(const float4*)(row + g)
                          : make_float4(0.f, 0.f, 0.f, 0.f);
      wr[4*s5+0] = v.x; wr[4*s5+1] = v.y; wr[4*s5+2] = v.z; wr[4*s5+3] = v.w;
    }
    const float Dd = Dv[d];
    #pragma unroll
    for (int k = 0; k < 4; ++k) {
      float acc = wr[16 + k] * Dd;          // skip connection u*D
      #pragma unroll
      for (int jp = 0; jp < 8; ++jp) {
        float klo = __builtin_bit_cast(float, kwp[k][jp] << 16);           // j=2jp
        float khi = __builtin_bit_cast(float, kwp[k][jp] & 0xffff0000u);   // j=2jp+1
        acc = fmaf(klo, wr[16 + k - 2*jp], acc);
        acc = fmaf(khi, wr[16 + k - 2*jp - 1], acc);
      }
      y[c][k] = acc;
      ps[k] = fmaf(acc, acc, ps[k]);
    }
  }

  __shared__ float ss[8][132];
  #pragma unroll
  for (int k = 0; k < 4; ++k) ss[4*tg + k][dr] = ps[k];
  __syncthreads();
  __shared__ float rsq[8];
  if (threadIdx.x < 8) {
    float s = 0.f;
    #pragma unroll
    for (int i = 0; i < 32; ++i) {
      float4 v = *(const float4*)&ss[threadIdx.x][4*i];
      s += (v.x + v.y) + (v.z + v.w);
    }
    rsq[threadIdx.x] = rsqrtf(s * (1.f/1024.f) + RMS_EPS);
  }
  __syncthreads();
  float rq[4];
  #pragma unroll
  for (int k = 0; k < 4; ++k) rq[k] = rsq[4*tg + k];
  #pragma unroll
  for (int c = 0; c < 8; ++c) {
    const int d = dr + 128*c;
    const float wn = nw[d];
    float4 o;
    o.x = y[c][0] * rq[0] * wn;
    o.y = y[c][1] * rq[1] * wn;
    o.z = y[c][2] * rq[2] * wn;
    o.w = y[c][3] * rq[3] * wn;
    *(float4*)(ob + (size_t)d * LS + t0 + 4*tg) = o;
  }
}

// ---------------------------------------------------------------------------
extern "C" void kernel_launch(void* const* d_in, const int* in_sizes, int n_in,
                              void* d_out, int out_size, void* d_ws, size_t ws_size,
                              hipStream_t stream) {
  // inputs: [0]=L(int,1), [1]=u, [2]=A, [3]=B, [4]=C, [5]=D, [6]=norm_w
  const float* u  = (const float*)d_in[1];
  const float* A  = (const float*)d_in[2];
  const float* B  = (const float*)d_in[3];
  const float* C  = (const float*)d_in[4];
  const float* Dv = (const float*)d_in[5];
  const float* nw = (const float*)d_in[6];
  float* out = (float*)d_out;

  // workspace carve (4.5 MB total)
  float*    BuCuT = (float*)d_ws;                                      // 4 MB
  uint32_t* Kwp   = (uint32_t*)((char*)d_ws + (4u << 20));             // 256 KB
  unsigned short* Bbf = (unsigned short*)((char*)d_ws + (4u << 20) + (256u << 10)); // 256 KB

  k0_prep<<<dim3(128),    dim3(256), 0, stream>>>(B, C, Bbf);
  k1_gemm<<<dim3(128, 4), dim3(512), 0, stream>>>(u, Bbf, BuCuT);
  k2_kw  <<<dim3(128, 4), dim3(256), 0, stream>>>(BuCuT, A, Kwp);
  k3_conv<<<dim3(256, 4), dim3(256), 0, stream>>>(u, Kwp, Dv, nw, out);
}

// Round 4
// 298.581 us; speedup vs baseline: 1.0773x; 1.0773x over previous
//
#include <hip/hip_runtime.h>
#include <stdint.h>

#define DM 1024
#define LS 2048
#define RMS_EPS 1.1920928955078125e-07f
#define S2 0.0029296875f   // BC_SCALE^2 = 3/1024, exact in fp32

typedef __attribute__((ext_vector_type(8))) short bf16x8;
typedef __attribute__((ext_vector_type(4))) float f32x4;

__device__ __forceinline__ unsigned short f2bf(float f) {
  uint32_t u = __builtin_bit_cast(uint32_t, f);
  u += 0x7FFFu + ((u >> 16) & 1u);   // round-to-nearest-even
  return (unsigned short)(u >> 16);
}

// ---------------------------------------------------------------------------
// K0: pack B (64x1024) and C (64x1024) fp32 -> stacked bf16 [128][1024]
// ---------------------------------------------------------------------------
__global__ __launch_bounds__(256) void k0_prep(const float* __restrict__ B,
                                               const float* __restrict__ C,
                                               unsigned short* __restrict__ Bbf) {
  int i4 = blockIdx.x * 256 + threadIdx.x;          // 0..32767 float4s
  const float4* src = (i4 < 16384) ? (const float4*)B : (const float4*)C;
  float4 v = src[i4 & 16383];
  ushort4 o;
  o.x = f2bf(v.x); o.y = f2bf(v.y); o.z = f2bf(v.z); o.w = f2bf(v.w);
  ((ushort4*)Bbf)[i4] = o;
}

// ---------------------------------------------------------------------------
// K1 (R2-proven v2): BuCuT[b][l][128] = ([B;C] @ u[b])^T via 16x16x32 MFMA.
// grid (128,4)=512 blocks (2/CU), block 256 (4 waves).
// Staging: 16 coalesced float4 loads/thread along l, f2bf, pack 8 k-contig
// bf16 -> ds_write_b128 into tile[k8][col^(k8&3)] = exact MFMA B-fragment.
// Wave w computes rows [32w,32w+32) x 16 cols; A-frags direct from L2 Bbf.
// ---------------------------------------------------------------------------
__global__ __launch_bounds__(256) void k1_gemm(const float* __restrict__ u,
                                               const unsigned short* __restrict__ Bbf,
                                               float* __restrict__ BuCuT) {
  const int b    = blockIdx.y;
  const int l0   = blockIdx.x * 16;
  const int lane = threadIdx.x & 63;
  const int w    = threadIdx.x >> 6;
  const float* ub = u + (size_t)b * DM * LS;

  __shared__ bf16x8 tile[128][16];   // 32 KB

  { // ---- stage: wave w covers k in [256w, 256w+256) ----
    const int lq = lane & 3;          // col quad: cols 4lq..4lq+3
    const int kg = lane >> 2;         // 0..15 -> 16 k-rows each
    const int kbase = 256 * w + 16 * kg;
    #pragma unroll
    for (int h = 0; h < 2; ++h) {
      float4 vv[8];
      #pragma unroll
      for (int r = 0; r < 8; ++r)
        vv[r] = *(const float4*)(ub + (size_t)(kbase + 8*h + r) * LS + l0 + 4*lq);
      const int k8 = 32*w + 2*kg + h;
      #pragma unroll
      for (int c = 0; c < 4; ++c) {
        union { bf16x8 v; unsigned short s[8]; } t;
        #pragma unroll
        for (int r = 0; r < 8; ++r) t.s[r] = f2bf(((const float*)&vv[r])[c]);
        tile[k8][(4*lq + c) ^ (k8 & 3)] = t.v;
      }
    }
  }
  __syncthreads();

  // ---- compute: M=32 rows per wave, N=16, K=1024 ----
  const int n = lane & 15;
  const int q = lane >> 4;
  f32x4 acc[2] = {};
  #pragma unroll 4
  for (int it = 0; it < 32; ++it) {
    bf16x8 bfrag = tile[4*it + q][n ^ q];
    #pragma unroll
    for (int rt = 0; rt < 2; ++rt) {
      int row = 32*w + 16*rt + n;
      bf16x8 a = *(const bf16x8*)(Bbf + (size_t)row * DM + 32*it + 8*q);
      acc[rt] = __builtin_amdgcn_mfma_f32_16x16x32_bf16(a, bfrag, acc[rt], 0, 0, 0);
    }
  }

  float* ob = BuCuT + (size_t)b * LS * 128;
  #pragma unroll
  for (int rt = 0; rt < 2; ++rt) {
    int col = l0 + n;                 // C/D: col = lane&15
    int row = 32*w + 16*rt + 4*q;     // row = 4*(lane>>4) + reg
    *(f32x4*)(ob + (size_t)col * 128 + row) = acc[rt];
  }
}

// ---------------------------------------------------------------------------
// K2 (R2 shape, packed out): Kw[b][t][j] = S2*sum_n Cu[n,t]*A[n]^j*Bu[n,t-j],
// emitted packed bf16 pairs. grid (64,4)=256 blocks, block 128, t-tile 32.
// thread = (tl=tid>>2 -> t, p=tid&3 -> n in [16p,16p+16)).
// ---------------------------------------------------------------------------
__global__ __launch_bounds__(128) void k2_kw(const float* __restrict__ BuCuT,
                                             const float* __restrict__ A,
                                             uint32_t* __restrict__ Kwp) {
  const int b  = blockIdx.y;
  const int t0 = blockIdx.x * 32;
  const int tl = threadIdx.x >> 2;    // 0..31
  const int p  = threadIdx.x & 3;
  const int t  = t0 + tl;
  const float* base = BuCuT + (size_t)b * LS * 128;

  float pw[16], aa[16];
  #pragma unroll
  for (int i = 0; i < 4; ++i) {
    float4 c4 = *(const float4*)(base + (size_t)t * 128 + 64 + 16*p + 4*i);
    float4 a4 = *(const float4*)(A + 16*p + 4*i);
    pw[4*i+0] = c4.x * S2; aa[4*i+0] = a4.x;
    pw[4*i+1] = c4.y * S2; aa[4*i+1] = a4.y;
    pw[4*i+2] = c4.z * S2; aa[4*i+2] = a4.z;
    pw[4*i+3] = c4.w * S2; aa[4*i+3] = a4.w;
  }
  float part[16];
  #pragma unroll
  for (int j = 0; j < 16; ++j) {
    float s = 0.f;
    if (t - j >= 0) {
      const float* bu = base + (size_t)(t - j) * 128 + 16*p;
      #pragma unroll
      for (int i = 0; i < 16; i += 4) {
        float4 b4 = *(const float4*)(bu + i);
        s = fmaf(pw[i+0], b4.x, s); s = fmaf(pw[i+1], b4.y, s);
        s = fmaf(pw[i+2], b4.z, s); s = fmaf(pw[i+3], b4.w, s);
      }
    }
    part[j] = s;
    #pragma unroll
    for (int i = 0; i < 16; ++i) pw[i] *= aa[i];   // pw = Cu*S2*A^j
  }
  __shared__ float ss[32][68];
  #pragma unroll
  for (int j = 0; j < 16; ++j) ss[tl][p*17 + j] = part[j];
  __syncthreads();
  const int o  = threadIdx.x * 4;     // 512 outputs, 4 per thread
  const int t2 = o >> 4;              // 0..31
  const int j0 = o & 15;              // in {0,4,8,12}
  float4 r;
  r.x = ss[t2][j0+0] + ss[t2][17+j0+0] + ss[t2][34+j0+0] + ss[t2][51+j0+0];
  r.y = ss[t2][j0+1] + ss[t2][17+j0+1] + ss[t2][34+j0+1] + ss[t2][51+j0+1];
  r.z = ss[t2][j0+2] + ss[t2][17+j0+2] + ss[t2][34+j0+2] + ss[t2][51+j0+2];
  r.w = ss[t2][j0+3] + ss[t2][17+j0+3] + ss[t2][34+j0+3] + ss[t2][51+j0+3];
  uint2 pp;
  pp.x = (uint32_t)f2bf(r.x) | ((uint32_t)f2bf(r.y) << 16);
  pp.y = (uint32_t)f2bf(r.z) | ((uint32_t)f2bf(r.w) << 16);
  *(uint2*)(Kwp + ((size_t)b * LS + t0 + t2) * 8 + (j0 >> 1)) = pp;
}

// ---------------------------------------------------------------------------
// K3 v4: fused conv(W=16) + u*D skip + RMSNorm(d) + norm_w + store.
// grid (128,4)=512 blocks (2/CU), block 512 (8 waves -> 16 waves/CU), t-tile 16
// so every d-row gets a FULL 64 B line write (the R3 killer was 32 B writes).
// thread: tg=tid&3 -> 4 consecutive t, dr=tid>>2 -> 8 d-rows (dr+128c).
// Kw packed bf16 (32 regs) + y[8][4] (32 regs) -> ~110 VGPR, 4 waves/EU.
// ---------------------------------------------------------------------------
__global__ __launch_bounds__(512, 4) void k3_conv(const float* __restrict__ u,
                                                  const uint32_t* __restrict__ Kwp,
                                                  const float* __restrict__ Dv,
                                                  const float* __restrict__ nw,
                                                  float* __restrict__ out) {
  const int b  = blockIdx.y;
  const int t0 = blockIdx.x * 16;
  const int tg = threadIdx.x & 3;
  const int dr = threadIdx.x >> 2;          // 0..127
  const float* ub = u + (size_t)b * DM * LS;
  float* ob = out + (size_t)b * DM * LS;

  uint32_t kwp[4][8];
  #pragma unroll
  for (int k = 0; k < 4; ++k) {
    const uint32_t* kp = Kwp + ((size_t)b * LS + t0 + 4*tg + k) * 8;
    *(uint4*)&kwp[k][0] = *(const uint4*)kp;
    *(uint4*)&kwp[k][4] = *(const uint4*)(kp + 4);
  }

  const int cbase = t0 - 16 + 4*tg;         // aligned window start
  float y[8][4];
  float ps[4] = {0.f, 0.f, 0.f, 0.f};
  #pragma unroll
  for (int c = 0; c < 8; ++c) {
    const int d = dr + 128*c;
    const float* row = ub + (size_t)d * LS;
    float wr[20];
    #pragma unroll
    for (int s5 = 0; s5 < 5; ++s5) {
      int g = cbase + 4*s5;
      float4 v = (g >= 0) ? *(const float4*)(row + g)
                          : make_float4(0.f, 0.f, 0.f, 0.f);
      wr[4*s5+0] = v.x; wr[4*s5+1] = v.y; wr[4*s5+2] = v.z; wr[4*s5+3] = v.w;
    }
    const float Dd = Dv[d];
    #pragma unroll
    for (int k = 0; k < 4; ++k) {
      float acc = wr[16 + k] * Dd;          // skip connection u*D
      #pragma unroll
      for (int jp = 0; jp < 8; ++jp) {
        float klo = __builtin_bit_cast(float, kwp[k][jp] << 16);           // j=2jp
        float khi = __builtin_bit_cast(float, kwp[k][jp] & 0xffff0000u);   // j=2jp+1
        acc = fmaf(klo, wr[16 + k - 2*jp], acc);
        acc = fmaf(khi, wr[16 + k - 2*jp - 1], acc);
      }
      y[c][k] = acc;
      ps[k] = fmaf(acc, acc, ps[k]);
    }
  }

  __shared__ float ss[16][132];
  #pragma unroll
  for (int k = 0; k < 4; ++k) ss[4*tg + k][dr] = ps[k];
  __syncthreads();
  __shared__ float rsq[16];
  if (threadIdx.x < 16) {
    float s = 0.f;
    #pragma unroll
    for (int i = 0; i < 32; ++i) {
      float4 v = *(const float4*)&ss[threadIdx.x][4*i];
      s += (v.x + v.y) + (v.z + v.w);
    }
    rsq[threadIdx.x] = rsqrtf(s * (1.f/1024.f) + RMS_EPS);
  }
  __syncthreads();
  float rq[4];
  #pragma unroll
  for (int k = 0; k < 4; ++k) rq[k] = rsq[4*tg + k];
  #pragma unroll
  for (int c = 0; c < 8; ++c) {
    const int d = dr + 128*c;
    const float wn = nw[d];
    float4 o;
    o.x = y[c][0] * rq[0] * wn;
    o.y = y[c][1] * rq[1] * wn;
    o.z = y[c][2] * rq[2] * wn;
    o.w = y[c][3] * rq[3] * wn;
    *(float4*)(ob + (size_t)d * LS + t0 + 4*tg) = o;
  }
}

// ---------------------------------------------------------------------------
extern "C" void kernel_launch(void* const* d_in, const int* in_sizes, int n_in,
                              void* d_out, int out_size, void* d_ws, size_t ws_size,
                              hipStream_t stream) {
  // inputs: [0]=L(int,1), [1]=u, [2]=A, [3]=B, [4]=C, [5]=D, [6]=norm_w
  const float* u  = (const float*)d_in[1];
  const float* A  = (const float*)d_in[2];
  const float* B  = (const float*)d_in[3];
  const float* C  = (const float*)d_in[4];
  const float* Dv = (const float*)d_in[5];
  const float* nw = (const float*)d_in[6];
  float* out = (float*)d_out;

  // workspace carve (4.5 MB total)
  float*    BuCuT = (float*)d_ws;                                      // 4 MB
  uint32_t* Kwp   = (uint32_t*)((char*)d_ws + (4u << 20));             // 256 KB
  unsigned short* Bbf = (unsigned short*)((char*)d_ws + (4u << 20) + (256u << 10)); // 256 KB

  k0_prep<<<dim3(128),    dim3(256), 0, stream>>>(B, C, Bbf);
  k1_gemm<<<dim3(128, 4), dim3(256), 0, stream>>>(u, Bbf, BuCuT);
  k2_kw  <<<dim3(64, 4),  dim3(128), 0, stream>>>(BuCuT, A, Kwp);
  k3_conv<<<dim3(128, 4), dim3(512), 0, stream>>>(u, Kwp, Dv, nw, out);
}

// Round 5
// 153.292 us; speedup vs baseline: 2.0983x; 1.9478x over previous
//
#include <hip/hip_runtime.h>
#include <stdint.h>

#define DM 1024
#define LS 2048
#define RMS_EPS 1.1920928955078125e-07f
#define S2 0.0029296875f   // BC_SCALE^2 = 3/1024, exact in fp32

typedef __attribute__((ext_vector_type(8))) short bf16x8;
typedef __attribute__((ext_vector_type(4))) float f32x4;

__device__ __forceinline__ unsigned short f2bf(float f) {
  uint32_t u = __builtin_bit_cast(uint32_t, f);
  u += 0x7FFFu + ((u >> 16) & 1u);   // round-to-nearest-even
  return (unsigned short)(u >> 16);
}

// ---------------------------------------------------------------------------
// K0: pack B (64x1024) and C (64x1024) fp32 -> stacked bf16 [128][1024]
// ---------------------------------------------------------------------------
__global__ __launch_bounds__(256) void k0_prep(const float* __restrict__ B,
                                               const float* __restrict__ C,
                                               unsigned short* __restrict__ Bbf) {
  int i4 = blockIdx.x * 256 + threadIdx.x;          // 0..32767 float4s
  const float4* src = (i4 < 16384) ? (const float4*)B : (const float4*)C;
  float4 v = src[i4 & 16383];
  ushort4 o;
  o.x = f2bf(v.x); o.y = f2bf(v.y); o.z = f2bf(v.z); o.w = f2bf(v.w);
  ((ushort4*)Bbf)[i4] = o;
}

// ---------------------------------------------------------------------------
// K1 (R2-proven v2): BuCuT[b][l][128] = ([B;C] @ u[b])^T via 16x16x32 MFMA.
// grid (128,4)=512 blocks (2/CU), block 256 (4 waves).
// ---------------------------------------------------------------------------
__global__ __launch_bounds__(256) void k1_gemm(const float* __restrict__ u,
                                               const unsigned short* __restrict__ Bbf,
                                               float* __restrict__ BuCuT) {
  const int b    = blockIdx.y;
  const int l0   = blockIdx.x * 16;
  const int lane = threadIdx.x & 63;
  const int w    = threadIdx.x >> 6;
  const float* ub = u + (size_t)b * DM * LS;

  __shared__ bf16x8 tile[128][16];   // 32 KB

  { // ---- stage: wave w covers k in [256w, 256w+256) ----
    const int lq = lane & 3;          // col quad: cols 4lq..4lq+3
    const int kg = lane >> 2;         // 0..15 -> 16 k-rows each
    const int kbase = 256 * w + 16 * kg;
    #pragma unroll
    for (int h = 0; h < 2; ++h) {
      float4 vv[8];
      #pragma unroll
      for (int r = 0; r < 8; ++r)
        vv[r] = *(const float4*)(ub + (size_t)(kbase + 8*h + r) * LS + l0 + 4*lq);
      const int k8 = 32*w + 2*kg + h;
      #pragma unroll
      for (int c = 0; c < 4; ++c) {
        union { bf16x8 v; unsigned short s[8]; } t;
        #pragma unroll
        for (int r = 0; r < 8; ++r) t.s[r] = f2bf(((const float*)&vv[r])[c]);
        tile[k8][(4*lq + c) ^ (k8 & 3)] = t.v;
      }
    }
  }
  __syncthreads();

  // ---- compute: M=32 rows per wave, N=16, K=1024 ----
  const int n = lane & 15;
  const int q = lane >> 4;
  f32x4 acc[2] = {};
  #pragma unroll 4
  for (int it = 0; it < 32; ++it) {
    bf16x8 bfrag = tile[4*it + q][n ^ q];
    #pragma unroll
    for (int rt = 0; rt < 2; ++rt) {
      int row = 32*w + 16*rt + n;
      bf16x8 a = *(const bf16x8*)(Bbf + (size_t)row * DM + 32*it + 8*q);
      acc[rt] = __builtin_amdgcn_mfma_f32_16x16x32_bf16(a, bfrag, acc[rt], 0, 0, 0);
    }
  }

  float* ob = BuCuT + (size_t)b * LS * 128;
  #pragma unroll
  for (int rt = 0; rt < 2; ++rt) {
    int col = l0 + n;                 // C/D: col = lane&15
    int row = 32*w + 16*rt + 4*q;     // row = 4*(lane>>4) + reg
    *(f32x4*)(ob + (size_t)col * 128 + row) = acc[rt];
  }
}

// ---------------------------------------------------------------------------
// K2: Kw[b][t][j] = S2*sum_n Cu[n,t]*A[n]^j*Bu[n,t-j], packed bf16 pairs.
// grid (64,4)=256 blocks, block 128, t-tile 32.
// ---------------------------------------------------------------------------
__global__ __launch_bounds__(128) void k2_kw(const float* __restrict__ BuCuT,
                                             const float* __restrict__ A,
                                             uint32_t* __restrict__ Kwp) {
  const int b  = blockIdx.y;
  const int t0 = blockIdx.x * 32;
  const int tl = threadIdx.x >> 2;    // 0..31
  const int p  = threadIdx.x & 3;
  const int t  = t0 + tl;
  const float* base = BuCuT + (size_t)b * LS * 128;

  float pw[16], aa[16];
  #pragma unroll
  for (int i = 0; i < 4; ++i) {
    float4 c4 = *(const float4*)(base + (size_t)t * 128 + 64 + 16*p + 4*i);
    float4 a4 = *(const float4*)(A + 16*p + 4*i);
    pw[4*i+0] = c4.x * S2; aa[4*i+0] = a4.x;
    pw[4*i+1] = c4.y * S2; aa[4*i+1] = a4.y;
    pw[4*i+2] = c4.z * S2; aa[4*i+2] = a4.z;
    pw[4*i+3] = c4.w * S2; aa[4*i+3] = a4.w;
  }
  float part[16];
  #pragma unroll
  for (int j = 0; j < 16; ++j) {
    float s = 0.f;
    if (t - j >= 0) {
      const float* bu = base + (size_t)(t - j) * 128 + 16*p;
      #pragma unroll
      for (int i = 0; i < 16; i += 4) {
        float4 b4 = *(const float4*)(bu + i);
        s = fmaf(pw[i+0], b4.x, s); s = fmaf(pw[i+1], b4.y, s);
        s = fmaf(pw[i+2], b4.z, s); s = fmaf(pw[i+3], b4.w, s);
      }
    }
    part[j] = s;
    #pragma unroll
    for (int i = 0; i < 16; ++i) pw[i] *= aa[i];   // pw = Cu*S2*A^j
  }
  __shared__ float ss[32][68];
  #pragma unroll
  for (int j = 0; j < 16; ++j) ss[tl][p*17 + j] = part[j];
  __syncthreads();
  const int o  = threadIdx.x * 4;     // 512 outputs, 4 per thread
  const int t2 = o >> 4;              // 0..31
  const int j0 = o & 15;              // in {0,4,8,12}
  float4 r;
  r.x = ss[t2][j0+0] + ss[t2][17+j0+0] + ss[t2][34+j0+0] + ss[t2][51+j0+0];
  r.y = ss[t2][j0+1] + ss[t2][17+j0+1] + ss[t2][34+j0+1] + ss[t2][51+j0+1];
  r.z = ss[t2][j0+2] + ss[t2][17+j0+2] + ss[t2][34+j0+2] + ss[t2][51+j0+2];
  r.w = ss[t2][j0+3] + ss[t2][17+j0+3] + ss[t2][34+j0+3] + ss[t2][51+j0+3];
  uint2 pp;
  pp.x = (uint32_t)f2bf(r.x) | ((uint32_t)f2bf(r.y) << 16);
  pp.y = (uint32_t)f2bf(r.z) | ((uint32_t)f2bf(r.w) << 16);
  *(uint2*)(Kwp + ((size_t)b * LS + t0 + t2) * 8 + (j0 >> 1)) = pp;
}

// ---------------------------------------------------------------------------
// K3 v5: fused conv(W=16) + u*D skip + RMSNorm(d) + norm_w + store.
// grid (128,4)=512 blocks, block 1024 (16 waves = 50% occupancy from ONE
// resident block). t-tile 16 (full 64B line per d-row write).
// thread: tg=tid&3 -> 4 consecutive t, dr=tid>>2 (0..255) -> 4 d-rows.
// Per-thread state: y[4][4]=16 + packed kwp[4][8]=32 + wr[20] => ~100 VGPR.
// NOTE: no second __launch_bounds__ arg — on gfx950 it makes the allocator
// chase max waves-per-EU and SPILL (R3/R4: VGPR clamped to 64, 280 MB of
// scratch traffic). The 1024-thread block itself enforces the 128-VGPR cap.
// ---------------------------------------------------------------------------
__global__ __launch_bounds__(1024) void k3_conv(const float* __restrict__ u,
                                                const uint32_t* __restrict__ Kwp,
                                                const float* __restrict__ Dv,
                                                const float* __restrict__ nw,
                                                float* __restrict__ out) {
  const int b  = blockIdx.y;
  const int t0 = blockIdx.x * 16;
  const int tg = threadIdx.x & 3;
  const int dr = threadIdx.x >> 2;          // 0..255
  const float* ub = u + (size_t)b * DM * LS;
  float* ob = out + (size_t)b * DM * LS;

  uint32_t kwp[4][8];
  #pragma unroll
  for (int k = 0; k < 4; ++k) {
    const uint32_t* kp = Kwp + ((size_t)b * LS + t0 + 4*tg + k) * 8;
    *(uint4*)&kwp[k][0] = *(const uint4*)kp;
    *(uint4*)&kwp[k][4] = *(const uint4*)(kp + 4);
  }

  const int cbase = t0 - 16 + 4*tg;         // aligned window start
  float y[4][4];
  float ps[4] = {0.f, 0.f, 0.f, 0.f};
  #pragma unroll 1
  for (int c = 0; c < 4; ++c) {
    const int d = dr + 256*c;
    const float* row = ub + (size_t)d * LS;
    float wr[20];
    #pragma unroll
    for (int s5 = 0; s5 < 5; ++s5) {
      int g = cbase + 4*s5;
      float4 v = (g >= 0) ? *(const float4*)(row + g)
                          : make_float4(0.f, 0.f, 0.f, 0.f);
      wr[4*s5+0] = v.x; wr[4*s5+1] = v.y; wr[4*s5+2] = v.z; wr[4*s5+3] = v.w;
    }
    const float Dd = Dv[d];
    #pragma unroll
    for (int k = 0; k < 4; ++k) {
      float acc = wr[16 + k] * Dd;          // skip connection u*D
      #pragma unroll
      for (int jp = 0; jp < 8; ++jp) {
        float klo = __builtin_bit_cast(float, kwp[k][jp] << 16);           // j=2jp
        float khi = __builtin_bit_cast(float, kwp[k][jp] & 0xffff0000u);   // j=2jp+1
        acc = fmaf(klo, wr[16 + k - 2*jp], acc);
        acc = fmaf(khi, wr[16 + k - 2*jp - 1], acc);
      }
      y[c][k] = acc;
      ps[k] = fmaf(acc, acc, ps[k]);
    }
  }

  // RMS reduction: ss[t][dr], stride 260 (= 4 mod 32 -> worst 2-way, free)
  __shared__ float ss[16][260];
  #pragma unroll
  for (int k = 0; k < 4; ++k) ss[4*tg + k][dr] = ps[k];
  __syncthreads();
  __shared__ float rsq[16];
  {
    const int w = threadIdx.x >> 6;         // wave 0..15 handles t-row w
    const int l = threadIdx.x & 63;
    float s = ss[w][l] + ss[w][l + 64] + ss[w][l + 128] + ss[w][l + 192];
    #pragma unroll
    for (int off = 32; off > 0; off >>= 1) s += __shfl_down(s, off, 64);
    if (l == 0) rsq[w] = rsqrtf(s * (1.f/1024.f) + RMS_EPS);
  }
  __syncthreads();
  float rq[4];
  #pragma unroll
  for (int k = 0; k < 4; ++k) rq[k] = rsq[4*tg + k];
  #pragma unroll
  for (int c = 0; c < 4; ++c) {
    const int d = dr + 256*c;
    const float wn = nw[d];
    float4 o;
    o.x = y[c][0] * rq[0] * wn;
    o.y = y[c][1] * rq[1] * wn;
    o.z = y[c][2] * rq[2] * wn;
    o.w = y[c][3] * rq[3] * wn;
    *(float4*)(ob + (size_t)d * LS + t0 + 4*tg) = o;
  }
}

// ---------------------------------------------------------------------------
extern "C" void kernel_launch(void* const* d_in, const int* in_sizes, int n_in,
                              void* d_out, int out_size, void* d_ws, size_t ws_size,
                              hipStream_t stream) {
  // inputs: [0]=L(int,1), [1]=u, [2]=A, [3]=B, [4]=C, [5]=D, [6]=norm_w
  const float* u  = (const float*)d_in[1];
  const float* A  = (const float*)d_in[2];
  const float* B  = (const float*)d_in[3];
  const float* C  = (const float*)d_in[4];
  const float* Dv = (const float*)d_in[5];
  const float* nw = (const float*)d_in[6];
  float* out = (float*)d_out;

  // workspace carve (4.5 MB total)
  float*    BuCuT = (float*)d_ws;                                      // 4 MB
  uint32_t* Kwp   = (uint32_t*)((char*)d_ws + (4u << 20));             // 256 KB
  unsigned short* Bbf = (unsigned short*)((char*)d_ws + (4u << 20) + (256u << 10)); // 256 KB

  k0_prep<<<dim3(128),    dim3(256),  0, stream>>>(B, C, Bbf);
  k1_gemm<<<dim3(128, 4), dim3(256),  0, stream>>>(u, Bbf, BuCuT);
  k2_kw  <<<dim3(64, 4),  dim3(128),  0, stream>>>(BuCuT, A, Kwp);
  k3_conv<<<dim3(128, 4), dim3(1024), 0, stream>>>(u, Kwp, Dv, nw, out);
}

// Round 6
// 143.039 us; speedup vs baseline: 2.2487x; 1.0717x over previous
//
#include <hip/hip_runtime.h>
#include <stdint.h>

#define DM 1024
#define LS 2048
#define RMS_EPS 1.1920928955078125e-07f
#define S2 0.0029296875f   // BC_SCALE^2 = 3/1024, exact in fp32

typedef __attribute__((ext_vector_type(8))) short bf16x8;
typedef __attribute__((ext_vector_type(4))) float f32x4;

__device__ __forceinline__ unsigned short f2bf(float f) {
  uint32_t u = __builtin_bit_cast(uint32_t, f);
  u += 0x7FFFu + ((u >> 16) & 1u);   // round-to-nearest-even
  return (unsigned short)(u >> 16);
}

// ---------------------------------------------------------------------------
// K0: pack B (64x1024) and C (64x1024) fp32 -> stacked bf16 [128][1024]
// ---------------------------------------------------------------------------
__global__ __launch_bounds__(256) void k0_prep(const float* __restrict__ B,
                                               const float* __restrict__ C,
                                               unsigned short* __restrict__ Bbf) {
  int i4 = blockIdx.x * 256 + threadIdx.x;          // 0..32767 float4s
  const float4* src = (i4 < 16384) ? (const float4*)B : (const float4*)C;
  float4 v = src[i4 & 16383];
  ushort4 o;
  o.x = f2bf(v.x); o.y = f2bf(v.y); o.z = f2bf(v.z); o.w = f2bf(v.w);
  ((ushort4*)Bbf)[i4] = o;
}

// ---------------------------------------------------------------------------
// K1 (R2-proven): BuCuT[b][l][128] = ([B;C] @ u[b])^T via 16x16x32 MFMA.
// grid (128,4)=512 blocks (2/CU), block 256 (4 waves).
// ---------------------------------------------------------------------------
__global__ __launch_bounds__(256) void k1_gemm(const float* __restrict__ u,
                                               const unsigned short* __restrict__ Bbf,
                                               float* __restrict__ BuCuT) {
  const int b    = blockIdx.y;
  const int l0   = blockIdx.x * 16;
  const int lane = threadIdx.x & 63;
  const int w    = threadIdx.x >> 6;
  const float* ub = u + (size_t)b * DM * LS;

  __shared__ bf16x8 tile[128][16];   // 32 KB

  { // ---- stage: wave w covers k in [256w, 256w+256) ----
    const int lq = lane & 3;          // col quad: cols 4lq..4lq+3
    const int kg = lane >> 2;         // 0..15 -> 16 k-rows each
    const int kbase = 256 * w + 16 * kg;
    #pragma unroll
    for (int h = 0; h < 2; ++h) {
      float4 vv[8];
      #pragma unroll
      for (int r = 0; r < 8; ++r)
        vv[r] = *(const float4*)(ub + (size_t)(kbase + 8*h + r) * LS + l0 + 4*lq);
      const int k8 = 32*w + 2*kg + h;
      #pragma unroll
      for (int c = 0; c < 4; ++c) {
        union { bf16x8 v; unsigned short s[8]; } t;
        #pragma unroll
        for (int r = 0; r < 8; ++r) t.s[r] = f2bf(((const float*)&vv[r])[c]);
        tile[k8][(4*lq + c) ^ (k8 & 3)] = t.v;
      }
    }
  }
  __syncthreads();

  // ---- compute: M=32 rows per wave, N=16, K=1024 ----
  const int n = lane & 15;
  const int q = lane >> 4;
  f32x4 acc[2] = {};
  #pragma unroll 4
  for (int it = 0; it < 32; ++it) {
    bf16x8 bfrag = tile[4*it + q][n ^ q];
    #pragma unroll
    for (int rt = 0; rt < 2; ++rt) {
      int row = 32*w + 16*rt + n;
      bf16x8 a = *(const bf16x8*)(Bbf + (size_t)row * DM + 32*it + 8*q);
      acc[rt] = __builtin_amdgcn_mfma_f32_16x16x32_bf16(a, bfrag, acc[rt], 0, 0, 0);
    }
  }

  float* ob = BuCuT + (size_t)b * LS * 128;
  #pragma unroll
  for (int rt = 0; rt < 2; ++rt) {
    int col = l0 + n;                 // C/D: col = lane&15
    int row = 32*w + 16*rt + 4*q;     // row = 4*(lane>>4) + reg
    *(f32x4*)(ob + (size_t)col * 128 + row) = acc[rt];
  }
}

// ---------------------------------------------------------------------------
// K23: fused Kw-compute + conv(W=16) + u*D skip + RMSNorm(d) + store.
// grid (128,4)=512 blocks, block 1024 (16 waves/CU from one resident block;
// 1024-thread block enforces the 128-VGPR cap -> no spill, no launch_bounds
// min-waves arg — that caused the R3/R4 spill disaster).
// Phase A: stage BuCuT rows [t0-16, t0+16) (16 KB, coalesced) + A^j table.
// Phase B: Kw partials, thread=(t:16, p:16, jq:4), n-range [4p,4p+4).
// Phase C: reduce over p -> KwS[16][16] fp32.
// Phase D: conv with kw[4][16] fp32 in regs (broadcast LDS read), RMS, store.
// ---------------------------------------------------------------------------
__global__ __launch_bounds__(1024) void k23_conv(const float* __restrict__ u,
                                                 const float* __restrict__ BuCuT,
                                                 const float* __restrict__ A,
                                                 const float* __restrict__ Dv,
                                                 const float* __restrict__ nw,
                                                 float* __restrict__ out) {
  const int b   = blockIdx.y;
  const int t0  = blockIdx.x * 16;
  const int tid = threadIdx.x;
  const float* ub = u + (size_t)b * DM * LS;
  float* ob = out + (size_t)b * DM * LS;

  __shared__ float Row[32][132];     // staged BuCuT rows, stride 132 (=4 mod 32)
  __shared__ float apow[64][17];     // A[n]^j
  __shared__ float Part[256][20];    // row = 16*j + t, col = p (stride 20: aligned f4, <=2-way)
  __shared__ float KwS[16][20];      // final Kw, fp32
  __shared__ float ss[16][260];      // RMS partials
  __shared__ float rsq[16];

  { // ---- Phase A: stage 32 rows (halo t0-16 .. t0+15), fully coalesced ----
    const int r  = tid >> 5;
    const int c4 = tid & 31;
    const int g  = t0 - 16 + r;
    float4 v = (g >= 0) ? *(const float4*)(BuCuT + ((size_t)b * LS + g) * 128 + 4*c4)
                        : make_float4(0.f, 0.f, 0.f, 0.f);
    *(float4*)&Row[r][4*c4] = v;
  }
  if (tid < 64) {
    float a = A[tid], p = 1.f;
    #pragma unroll
    for (int j = 0; j < 16; ++j) { apow[tid][j] = p; p *= a; }
  }
  __syncthreads();

  { // ---- Phase B: partials. Bu = Row[.][0:64), Cu = Row[.][64:128) ----
    const int t  = tid & 15;
    const int p  = (tid >> 4) & 15;
    const int jq = tid >> 8;                  // 0..3
    float4 cu = *(const float4*)&Row[16 + t][64 + 4*p];
    float4 aa = *(const float4*)(A + 4*p);
    float pw[4];
    pw[0] = cu.x * S2 * apow[4*p+0][4*jq];
    pw[1] = cu.y * S2 * apow[4*p+1][4*jq];
    pw[2] = cu.z * S2 * apow[4*p+2][4*jq];
    pw[3] = cu.w * S2 * apow[4*p+3][4*jq];
    #pragma unroll
    for (int jj = 0; jj < 4; ++jj) {
      const int j = 4*jq + jj;
      float4 b4 = *(const float4*)&Row[16 + t - j][4*p];
      float s = pw[0]*b4.x + pw[1]*b4.y + pw[2]*b4.z + pw[3]*b4.w;
      Part[16*j + t][p] = s;
      pw[0] *= aa.x; pw[1] *= aa.y; pw[2] *= aa.z; pw[3] *= aa.w;
    }
  }
  __syncthreads();
  if (tid < 256) {                            // row tid = 16*j + t
    float s = 0.f;
    #pragma unroll
    for (int p4 = 0; p4 < 4; ++p4) {
      float4 v = *(const float4*)&Part[tid][4*p4];
      s += (v.x + v.y) + (v.z + v.w);
    }
    KwS[tid & 15][tid >> 4] = s;
  }
  __syncthreads();

  // ---- Phase D: conv + RMS + store ----
  const int tg = tid & 3;
  const int dr = tid >> 2;                    // 0..255
  float kw[4][16];
  #pragma unroll
  for (int k = 0; k < 4; ++k)
    #pragma unroll
    for (int i = 0; i < 4; ++i)
      *(float4*)&kw[k][4*i] = *(const float4*)&KwS[4*tg + k][4*i];  // broadcast

  const int cbase = t0 - 16 + 4*tg;           // aligned window start
  float y[4][4];
  float ps[4] = {0.f, 0.f, 0.f, 0.f};
  #pragma unroll 1
  for (int c = 0; c < 4; ++c) {
    const int d = dr + 256*c;
    const float* row = ub + (size_t)d * LS;
    float wr[20];
    #pragma unroll
    for (int s5 = 0; s5 < 5; ++s5) {
      int g = cbase + 4*s5;
      float4 v = (g >= 0) ? *(const float4*)(row + g)
                          : make_float4(0.f, 0.f, 0.f, 0.f);
      wr[4*s5+0] = v.x; wr[4*s5+1] = v.y; wr[4*s5+2] = v.z; wr[4*s5+3] = v.w;
    }
    const float Dd = Dv[d];
    #pragma unroll
    for (int k = 0; k < 4; ++k) {
      float acc = wr[16 + k] * Dd;            // skip connection u*D
      #pragma unroll
      for (int j = 0; j < 16; ++j)
        acc = fmaf(kw[k][j], wr[16 + k - j], acc);
      y[c][k] = acc;
      ps[k] = fmaf(acc, acc, ps[k]);
    }
  }

  #pragma unroll
  for (int k = 0; k < 4; ++k) ss[4*tg + k][dr] = ps[k];
  __syncthreads();
  {
    const int w = tid >> 6;                   // wave w reduces t-row w
    const int l = tid & 63;
    float s = ss[w][l] + ss[w][l + 64] + ss[w][l + 128] + ss[w][l + 192];
    #pragma unroll
    for (int off = 32; off > 0; off >>= 1) s += __shfl_down(s, off, 64);
    if (l == 0) rsq[w] = rsqrtf(s * (1.f/1024.f) + RMS_EPS);
  }
  __syncthreads();
  float rq[4];
  #pragma unroll
  for (int k = 0; k < 4; ++k) rq[k] = rsq[4*tg + k];
  #pragma unroll
  for (int c = 0; c < 4; ++c) {
    const int d = dr + 256*c;
    const float wn = nw[d];
    float4 o;
    o.x = y[c][0] * rq[0] * wn;
    o.y = y[c][1] * rq[1] * wn;
    o.z = y[c][2] * rq[2] * wn;
    o.w = y[c][3] * rq[3] * wn;
    *(float4*)(ob + (size_t)d * LS + t0 + 4*tg) = o;
  }
}

// ---------------------------------------------------------------------------
extern "C" void kernel_launch(void* const* d_in, const int* in_sizes, int n_in,
                              void* d_out, int out_size, void* d_ws, size_t ws_size,
                              hipStream_t stream) {
  // inputs: [0]=L(int,1), [1]=u, [2]=A, [3]=B, [4]=C, [5]=D, [6]=norm_w
  const float* u  = (const float*)d_in[1];
  const float* A  = (const float*)d_in[2];
  const float* B  = (const float*)d_in[3];
  const float* C  = (const float*)d_in[4];
  const float* Dv = (const float*)d_in[5];
  const float* nw = (const float*)d_in[6];
  float* out = (float*)d_out;

  // workspace carve (4.25 MB total)
  float* BuCuT = (float*)d_ws;                                         // 4 MB
  unsigned short* Bbf = (unsigned short*)((char*)d_ws + (4u << 20));   // 256 KB

  k0_prep <<<dim3(128),    dim3(256),  0, stream>>>(B, C, Bbf);
  k1_gemm <<<dim3(128, 4), dim3(256),  0, stream>>>(u, Bbf, BuCuT);
  k23_conv<<<dim3(128, 4), dim3(1024), 0, stream>>>(u, BuCuT, A, Dv, nw, out);
}